// Round 11
// baseline (240.765 us; speedup 1.0000x reference)
//
#include <hip/hip_runtime.h>

#define N_NODES 50000
#define N_EDGES 800000
#define IN_DIM 128
#define HID 64
#define N_GRAPHS 256

#define E_PER_BLK 4000
#define F_BLOCKS (N_EDGES / E_PER_BLK)      // 200
#define NBKT ((N_NODES + 255) / 256)        // 196 coarse buckets of 256 nodes
#define CNT_N (NBKT * F_BLOCKS)             // 39200
#define SCB ((CNT_N + 255) / 256)           // 154
#define NTILES (N_NODES / 4)                // 12500 (exact)

// NOTES:
// (r3-4) __launch_bounds__ min-waves arg => VGPR cap halved, ~1.1 GB scratch spill. Plain (256).
// (r5)   single-block scan = 125 us one-CU latency; hierarchical scans only.
// (r6)   GEMV with LDS-resident W was LDS-pipe-bound (256 DS ops/node).
// (r7)   atomic-cursor CSR fill (800K device atomics) -> LDS counting sort.
// (r8)   w[128]/lane -> compiler caps ~85 VGPR and REMATERIALIZES weight loads. Split-K pairs.
// (r9)   per-node barriers ate the gain -> 4-node tiles + bf16 node buffers.
// (r10)  gather now loads 2 edge-rows per instruction (uint chunks, 32 lanes/row);
//        mlp pipelined to 1 barrier/tile (output written one tile late).

__device__ __forceinline__ float bf2f(unsigned short v) {
  return __uint_as_float(((unsigned int)v) << 16);
}
__device__ __forceinline__ unsigned short f2bf(float f) {
  unsigned int u = __float_as_uint(f);
  return (unsigned short)((u + 0x7fffu + ((u >> 16) & 1u)) >> 16);  // RNE
}

// ---- F1: per-(block, coarse-bucket) histogram of dst ----
__global__ __launch_bounds__(256) void part_hist_kernel(const int* __restrict__ dst,
                                                        int* __restrict__ cnt) {
  __shared__ int h[NBKT];
  const int t = threadIdx.x;
  for (int k = t; k < NBKT; k += 256) h[k] = 0;
  __syncthreads();
  const int base = blockIdx.x * E_PER_BLK;
  for (int i = t; i < E_PER_BLK; i += 256) atomicAdd(&h[dst[base + i] >> 8], 1);
  __syncthreads();
  for (int k = t; k < NBKT; k += 256) cnt[k * F_BLOCKS + blockIdx.x] = h[k];
}

// ---- F2: flat hierarchical exclusive scan over CNT_N entries ----
__global__ __launch_bounds__(256) void scan1g_kernel(const int* __restrict__ in,
                                                     int* __restrict__ ex,
                                                     int* __restrict__ bsum, int n) {
  __shared__ int s[256];
  const int t = threadIdx.x;
  const int i = blockIdx.x * 256 + t;
  int v = (i < n) ? in[i] : 0;
  s[t] = v;
  __syncthreads();
#pragma unroll
  for (int ofs = 1; ofs < 256; ofs <<= 1) {
    int u = (t >= ofs) ? s[t - ofs] : 0;
    __syncthreads();
    s[t] += u;
    __syncthreads();
  }
  if (i < n) ex[i] = s[t] - v;
  if (t == 255) bsum[blockIdx.x] = s[255];
}

__global__ __launch_bounds__(256) void scan2g_kernel(const int* __restrict__ bsum,
                                                     int* __restrict__ bpref, int nb) {
  __shared__ int s[256];
  const int t = threadIdx.x;
  int v = (t < nb) ? bsum[t] : 0;
  s[t] = v;
  __syncthreads();
#pragma unroll
  for (int ofs = 1; ofs < 256; ofs <<= 1) {
    int u = (t >= ofs) ? s[t - ofs] : 0;
    __syncthreads();
    s[t] += u;
    __syncthreads();
  }
  if (t < nb) bpref[t] = s[t] - v;
}

__global__ __launch_bounds__(256) void scan3g_kernel(int* __restrict__ ex,
                                                     const int* __restrict__ bpref, int n) {
  const int i = blockIdx.x * 256 + threadIdx.x;
  if (i < n) ex[i] += bpref[blockIdx.x];
}

// ---- F3: partition edges into coarse-bucket order (LDS cursors) ----
__global__ __launch_bounds__(256) void part_scatter_kernel(const int* __restrict__ src,
                                                           const int* __restrict__ dst,
                                                           const int* __restrict__ cex,
                                                           int* __restrict__ psrc,
                                                           int* __restrict__ pdst) {
  __shared__ int cur[NBKT];
  const int t = threadIdx.x;
  for (int k = t; k < NBKT; k += 256) cur[k] = cex[k * F_BLOCKS + blockIdx.x];
  __syncthreads();
  const int base = blockIdx.x * E_PER_BLK;
  for (int i = t; i < E_PER_BLK; i += 256) {
    int d = dst[base + i], s = src[base + i];
    int p = atomicAdd(&cur[d >> 8], 1);
    pdst[p] = d;
    psrc[p] = s;
  }
}

// ---- F4: per-bucket local counting sort -> csr + off ----
__global__ __launch_bounds__(256) void bucket_sort_kernel(const int* __restrict__ psrc,
                                                          const int* __restrict__ pdst,
                                                          const int* __restrict__ cex,
                                                          int* __restrict__ csr,
                                                          int* __restrict__ off) {
  const int k = blockIdx.x;
  const int t = threadIdx.x;
  const int b0 = cex[k * F_BLOCKS];
  const int b1 = (k == NBKT - 1) ? N_EDGES : cex[(k + 1) * F_BLOCKS];
  __shared__ int cnt[256];
  __shared__ int s[256];
  __shared__ int cur[256];
  cnt[t] = 0;
  __syncthreads();
  for (int i = b0 + t; i < b1; i += 256) atomicAdd(&cnt[pdst[i] & 255], 1);
  __syncthreads();
  int v = cnt[t];
  s[t] = v;
  __syncthreads();
#pragma unroll
  for (int ofs = 1; ofs < 256; ofs <<= 1) {
    int u = (t >= ofs) ? s[t - ofs] : 0;
    __syncthreads();
    s[t] += u;
    __syncthreads();
  }
  const int node = (k << 8) + t;
  const int start = b0 + s[t] - v;
  cur[t] = start;
  if (node < N_NODES) off[node] = start;
  if (k == NBKT - 1 && t == 0) off[N_NODES] = N_EDGES;
  __syncthreads();
  for (int i = b0 + t; i < b1; i += 256) {
    int d = pdst[i];
    int p = atomicAdd(&cur[d & 255], 1);
    csr[p] = psrc[i];
  }
}

// ---- proj: h = relu(x @ Wp + bp). Split-K wave pairs, 4-node tiles, bf16 out ----
__global__ __launch_bounds__(256) void proj_kernel(
    const float* __restrict__ x, const float* __restrict__ Wp,
    const float* __restrict__ bp, unsigned short* __restrict__ h) {
  __shared__ __align__(16) float sX[2][2][4][64];     // [pair][khalf][t][k]
  __shared__ __align__(16) float sPart[2][2][4][64];  // [pair][buf][t][j]
  const int wave = threadIdx.x >> 6, lane = threadIdx.x & 63;
  const int pair = wave >> 1, khalf = wave & 1;
  float w[64];
#pragma unroll
  for (int k = 0; k < 64; ++k) w[k] = Wp[(khalf * 64 + k) * HID + lane];  // coalesced
  const float bias = bp[lane];
  const int pv = blockIdx.x * 2 + pair;
  const int np = gridDim.x * 2;
  const int iters = (NTILES - blockIdx.x * 2 + np - 1) / np;  // block-uniform
  for (int it = 0; it < iters; ++it) {
    const int tile = pv + it * np;
    const bool act = (tile < NTILES);
    const int n0 = tile * 4;
    const int buf = it & 1;
    if (act) {
#pragma unroll
      for (int t = 0; t < 4; ++t)
        sX[pair][khalf][t][lane] = x[(n0 + t) * IN_DIM + khalf * 64 + lane];
    }
    float p[4];
#pragma unroll
    for (int t = 0; t < 4; ++t) {
      float a0 = khalf ? 0.f : bias, a1 = 0.f, a2 = 0.f, a3 = 0.f;
#pragma unroll
      for (int k = 0; k < 64; k += 4) {
        float4 v = *(const float4*)&sX[pair][khalf][t][k];  // same-addr broadcast
        a0 = fmaf(v.x, w[k + 0], a0);
        a1 = fmaf(v.y, w[k + 1], a1);
        a2 = fmaf(v.z, w[k + 2], a2);
        a3 = fmaf(v.w, w[k + 3], a3);
      }
      p[t] = (a0 + a1) + (a2 + a3);
    }
    if (act && khalf) {
#pragma unroll
      for (int t = 0; t < 4; ++t) sPart[pair][buf][t][lane] = p[t];
    }
    __syncthreads();
    if (act && !khalf) {
#pragma unroll
      for (int t = 0; t < 4; ++t)
        h[(n0 + t) * HID + lane] = f2bf(fmaxf(p[t] + sPart[pair][buf][t][lane], 0.0f));
    }
  }
}

// ------- gather: agg[n] = h[n] + sum h[csr[e]] ; 2 edge-rows per load (uint chunks) -------
__global__ __launch_bounds__(256) void gather_kernel(
    const unsigned short* __restrict__ h, const int* __restrict__ off,
    const int* __restrict__ csr, unsigned short* __restrict__ agg) {
  const unsigned int* __restrict__ h2 = (const unsigned int*)h;
  unsigned int* __restrict__ agg2 = (unsigned int*)agg;
  const int lane = threadIdx.x & 63;
  const int half = lane >> 5;   // which edge of a pair
  const int c = lane & 31;      // uint chunk (2 bf16)
  const int wv = (blockIdx.x * 256 + threadIdx.x) >> 6;
  const int nw = (gridDim.x * 256) >> 6;
  for (int n = wv; n < N_NODES; n += nw) {
    const int o0 = off[n], o1 = off[n + 1];
    float ax0 = 0.f, ay0 = 0.f, ax1 = 0.f, ay1 = 0.f;
    float ax2 = 0.f, ay2 = 0.f, ax3 = 0.f, ay3 = 0.f;
    float ax4 = 0.f, ay4 = 0.f, ax5 = 0.f, ay5 = 0.f;
    float ax6 = 0.f, ay6 = 0.f, ax7 = 0.f, ay7 = 0.f;
    if (half == 0) {  // self (eps = 0), counted once
      unsigned int u = h2[n * 32 + c];
      ax0 = bf2f((unsigned short)(u & 0xffff));
      ay0 = bf2f((unsigned short)(u >> 16));
    }
    for (int base = o0; base < o1; base += 64) {
      const int cnt = min(64, o1 - base);
      int idxv = (lane < cnt) ? csr[base + lane] : 0;
      int k = 0;
      for (; k + 16 <= cnt; k += 16) {  // 8 load-pairs = 16 edges in flight
        int i0 = __shfl(idxv, k + 0 + half);
        int i1 = __shfl(idxv, k + 2 + half);
        int i2 = __shfl(idxv, k + 4 + half);
        int i3 = __shfl(idxv, k + 6 + half);
        int i4 = __shfl(idxv, k + 8 + half);
        int i5 = __shfl(idxv, k + 10 + half);
        int i6 = __shfl(idxv, k + 12 + half);
        int i7 = __shfl(idxv, k + 14 + half);
        unsigned int u0 = h2[i0 * 32 + c];
        unsigned int u1 = h2[i1 * 32 + c];
        unsigned int u2 = h2[i2 * 32 + c];
        unsigned int u3 = h2[i3 * 32 + c];
        unsigned int u4 = h2[i4 * 32 + c];
        unsigned int u5 = h2[i5 * 32 + c];
        unsigned int u6 = h2[i6 * 32 + c];
        unsigned int u7 = h2[i7 * 32 + c];
        ax0 += bf2f((unsigned short)(u0 & 0xffff)); ay0 += bf2f((unsigned short)(u0 >> 16));
        ax1 += bf2f((unsigned short)(u1 & 0xffff)); ay1 += bf2f((unsigned short)(u1 >> 16));
        ax2 += bf2f((unsigned short)(u2 & 0xffff)); ay2 += bf2f((unsigned short)(u2 >> 16));
        ax3 += bf2f((unsigned short)(u3 & 0xffff)); ay3 += bf2f((unsigned short)(u3 >> 16));
        ax4 += bf2f((unsigned short)(u4 & 0xffff)); ay4 += bf2f((unsigned short)(u4 >> 16));
        ax5 += bf2f((unsigned short)(u5 & 0xffff)); ay5 += bf2f((unsigned short)(u5 >> 16));
        ax6 += bf2f((unsigned short)(u6 & 0xffff)); ay6 += bf2f((unsigned short)(u6 >> 16));
        ax7 += bf2f((unsigned short)(u7 & 0xffff)); ay7 += bf2f((unsigned short)(u7 >> 16));
      }
      for (; k < cnt; k += 2) {  // tail, 2 edges at a time (high half predicated)
        int ke = k + half;
        int ie = __shfl(idxv, (ke < cnt) ? ke : k);
        unsigned int u = h2[ie * 32 + c];
        if (ke < cnt) {
          ax0 += bf2f((unsigned short)(u & 0xffff));
          ay0 += bf2f((unsigned short)(u >> 16));
        }
      }
    }
    float sx = ((ax0 + ax1) + (ax2 + ax3)) + ((ax4 + ax5) + (ax6 + ax7));
    float sy = ((ay0 + ay1) + (ay2 + ay3)) + ((ay4 + ay5) + (ay6 + ay7));
    sx += __shfl_xor(sx, 32);
    sy += __shfl_xor(sy, 32);
    if (half == 0)
      agg2[n * 32 + c] = (unsigned int)f2bf(sx) | ((unsigned int)f2bf(sy) << 16);
  }
}

// ---- mlp: out = relu(relu(in@W1+b1)@W2+b2). Split-K pairs, 4-node tiles,
//      1 barrier/tile (output pipelined one tile behind) ----
__global__ __launch_bounds__(256) void mlp_kernel(
    const unsigned short* __restrict__ agg, const float* __restrict__ W1,
    const float* __restrict__ b1, const float* __restrict__ W2,
    const float* __restrict__ b2, unsigned short* __restrict__ out) {
  __shared__ __align__(16) float sIn[2][2][4][32];       // [pair][khalf][t][k]
  __shared__ __align__(16) float sP[2][2][2][4][64];     // [pair][khalf][buf][t][j]
  __shared__ __align__(16) float sQ[2][2][4][64];        // [pair][buf][t][j]
  const int wave = threadIdx.x >> 6, lane = threadIdx.x & 63;
  const int pair = wave >> 1, khalf = wave & 1;
  float w1[32], w2[32];
#pragma unroll
  for (int k = 0; k < 32; ++k) w1[k] = W1[(khalf * 32 + k) * HID + lane];
#pragma unroll
  for (int k = 0; k < 32; ++k) w2[k] = W2[(khalf * 32 + k) * HID + lane];
  const float bias1 = b1[lane], bias2 = b2[lane];
  const int pv = blockIdx.x * 2 + pair;
  const int np = gridDim.x * 2;
  const int iters = (NTILES - blockIdx.x * 2 + np - 1) / np;  // block-uniform
  float p2[4];
  int prevN0 = -1, prevBuf = 0;
  for (int it = 0; it < iters; ++it) {
    const int tile = pv + it * np;
    const bool act = (tile < NTILES);
    const int n0 = tile * 4;
    const int buf = it & 1;
    if (act) {
#pragma unroll
      for (int t = 0; t < 4; ++t)
        sIn[pair][khalf][t][lane & 31] =
            bf2f(agg[(n0 + t) * HID + khalf * 32 + (lane & 31)]);
#pragma unroll
      for (int t = 0; t < 4; ++t) {
        float a0 = khalf ? 0.f : bias1, a1 = 0.f, a2 = 0.f, a3 = 0.f;
#pragma unroll
        for (int k = 0; k < 32; k += 4) {
          float4 v = *(const float4*)&sIn[pair][khalf][t][k];
          a0 = fmaf(v.x, w1[k + 0], a0);
          a1 = fmaf(v.y, w1[k + 1], a1);
          a2 = fmaf(v.z, w1[k + 2], a2);
          a3 = fmaf(v.w, w1[k + 3], a3);
        }
        sP[pair][khalf][buf][t][lane] = (a0 + a1) + (a2 + a3);
      }
    }
    __syncthreads();
    // write previous tile's output (sQ[prevBuf] made visible by the barrier above)
    if (prevN0 >= 0 && !khalf) {
#pragma unroll
      for (int t = 0; t < 4; ++t)
        out[(prevN0 + t) * HID + lane] =
            f2bf(fmaxf(p2[t] + sQ[pair][prevBuf][t][lane], 0.0f));
    }
    if (act) {
#pragma unroll
      for (int t = 0; t < 4; ++t) {
        float a0 = khalf ? 0.f : bias2, a1 = 0.f, a2 = 0.f, a3 = 0.f;
#pragma unroll
        for (int k = 0; k < 32; k += 4) {
          float4 pa = *(const float4*)&sP[pair][0][buf][t][khalf * 32 + k];
          float4 pb = *(const float4*)&sP[pair][1][buf][t][khalf * 32 + k];
          a0 = fmaf(fmaxf(pa.x + pb.x, 0.0f), w2[k + 0], a0);
          a1 = fmaf(fmaxf(pa.y + pb.y, 0.0f), w2[k + 1], a1);
          a2 = fmaf(fmaxf(pa.z + pb.z, 0.0f), w2[k + 2], a2);
          a3 = fmaf(fmaxf(pa.w + pb.w, 0.0f), w2[k + 3], a3);
        }
        p2[t] = (a0 + a1) + (a2 + a3);
      }
      if (khalf) {
#pragma unroll
        for (int t = 0; t < 4; ++t) sQ[pair][buf][t][lane] = p2[t];
      }
      prevN0 = n0;
      prevBuf = buf;
    } else {
      prevN0 = -1;
    }
  }
  __syncthreads();  // drain: make last sQ visible
  if (prevN0 >= 0 && !khalf) {
#pragma unroll
    for (int t = 0; t < 4; ++t)
      out[(prevN0 + t) * HID + lane] =
          f2bf(fmaxf(p2[t] + sQ[pair][prevBuf][t][lane], 0.0f));
  }
}

// ------- pool: batch sorted -> one block per graph, binary-search range -------
__global__ __launch_bounds__(256) void pool_kernel(const unsigned short* __restrict__ h,
                                                   const int* __restrict__ batch,
                                                   float* __restrict__ out) {
  const int g = blockIdx.x;
  int lo = 0, hi = N_NODES;
  while (lo < hi) {
    int mid = (lo + hi) >> 1;
    if (batch[mid] < g) lo = mid + 1; else hi = mid;
  }
  const int s = lo;
  hi = N_NODES;
  while (lo < hi) {
    int mid = (lo + hi) >> 1;
    if (batch[mid] < g + 1) lo = mid + 1; else hi = mid;
  }
  const int e = lo;
  const int wave = threadIdx.x >> 6, lane = threadIdx.x & 63;
  float a0 = 0.f, a1 = 0.f, a2 = 0.f, a3 = 0.f;
  int n = s + wave;
  for (; n + 12 < e; n += 16) {
    a0 += bf2f(h[n * HID + lane]);
    a1 += bf2f(h[(n + 4) * HID + lane]);
    a2 += bf2f(h[(n + 8) * HID + lane]);
    a3 += bf2f(h[(n + 12) * HID + lane]);
  }
  for (; n < e; n += 4) a0 += bf2f(h[n * HID + lane]);
  __shared__ float red[4][HID];
  red[wave][lane] = ((a0 + a1) + (a2 + a3));
  __syncthreads();
  if (wave == 0) {
    float v = red[0][lane] + red[1][lane] + red[2][lane] + red[3][lane];
    float cnt = (float)(e - s);
    out[g * HID + lane] = v / fmaxf(cnt, 1.0f);
  }
}

extern "C" void kernel_launch(void* const* d_in, const int* in_sizes, int n_in,
                              void* d_out, int out_size, void* d_ws, size_t ws_size,
                              hipStream_t stream) {
  const float* x    = (const float*)d_in[0];
  const int*   edge = (const int*)d_in[1];
  const int*   batch= (const int*)d_in[2];
  const float* Wp   = (const float*)d_in[3];
  const float* bp   = (const float*)d_in[4];
  const float* W1_0 = (const float*)d_in[5];
  const float* b1_0 = (const float*)d_in[6];
  const float* W2_0 = (const float*)d_in[7];
  const float* b2_0 = (const float*)d_in[8];
  const float* W1_1 = (const float*)d_in[9];
  const float* b1_1 = (const float*)d_in[10];
  const float* W2_1 = (const float*)d_in[11];
  const float* b2_1 = (const float*)d_in[12];
  const int* src = edge;
  const int* dst = edge + N_EDGES;
  float* out = (float*)d_out;

  const size_t NB = (size_t)N_NODES * HID;
  unsigned short* hA = (unsigned short*)d_ws;  // NB bf16
  unsigned short* hB = hA + NB;                // NB bf16
  int* off     = (int*)(hB + NB);   // N_NODES+1
  int* cnt     = off + N_NODES + 1; // CNT_N
  int* cex     = cnt + CNT_N;       // CNT_N
  int* sbsum   = cex + CNT_N;       // SCB
  int* sbpref  = sbsum + SCB;       // SCB
  int* pdst    = sbpref + SCB;      // N_EDGES
  int* psrc    = pdst + N_EDGES;    // N_EDGES
  int* csr     = psrc + N_EDGES;    // N_EDGES

  dim3 b256(256);

  // CSR build: counting sort, zero global atomics
  part_hist_kernel<<<F_BLOCKS, b256, 0, stream>>>(dst, cnt);
  scan1g_kernel<<<SCB, b256, 0, stream>>>(cnt, cex, sbsum, CNT_N);
  scan2g_kernel<<<1, b256, 0, stream>>>(sbsum, sbpref, SCB);
  scan3g_kernel<<<SCB, b256, 0, stream>>>(cex, sbpref, CNT_N);
  part_scatter_kernel<<<F_BLOCKS, b256, 0, stream>>>(src, dst, cex, psrc, pdst);
  bucket_sort_kernel<<<NBKT, b256, 0, stream>>>(psrc, pdst, cex, csr, off);

  // h0 -> hA
  proj_kernel<<<2048, b256, 0, stream>>>(x, Wp, bp, hA);

  // layer 0: gather A->B, mlp B->B (in-place)
  gather_kernel<<<12500, b256, 0, stream>>>(hA, off, csr, hB);
  mlp_kernel<<<2048, b256, 0, stream>>>(hB, W1_0, b1_0, W2_0, b2_0, hB);

  // layer 1: gather B->A, mlp A->A (in-place)
  gather_kernel<<<12500, b256, 0, stream>>>(hB, off, csr, hA);
  mlp_kernel<<<2048, b256, 0, stream>>>(hA, W1_1, b1_1, W2_1, b2_1, hA);

  // pool
  pool_kernel<<<N_GRAPHS, b256, 0, stream>>>(hA, batch, out);
}

// Round 12
// 174.852 us; speedup vs baseline: 1.3770x; 1.3770x over previous
//
#include <hip/hip_runtime.h>

#define N_NODES 50000
#define N_EDGES 800000
#define IN_DIM 128
#define HID 64
#define N_GRAPHS 256

#define E_PER_BLK 4000
#define F_BLOCKS (N_EDGES / E_PER_BLK)      // 200
#define NBKT ((N_NODES + 255) / 256)        // 196 coarse buckets of 256 nodes
#define CNT_N (NBKT * F_BLOCKS)             // 39200
#define SCB ((CNT_N + 255) / 256)           // 154
#define NTILES (N_NODES / 4)                // 12500 (exact)

// NOTES:
// (r3-4) __launch_bounds__ min-waves arg => VGPR cap halved, ~1.1 GB scratch spill. Plain (256).
// (r5)   single-block scan = 125 us one-CU latency; hierarchical scans only.
// (r6)   GEMV with LDS-resident W was LDS-pipe-bound (256 DS ops/node).
// (r7)   atomic-cursor CSR fill (800K device atomics) -> LDS counting sort.
// (r8)   w[128]/lane -> compiler caps ~85 VGPR and REMATERIALIZES weight loads. Split-K pairs.
// (r9)   per-node barriers ate the gain -> 4-node tiles + bf16 node buffers.
// (r10)  gather loads 2 edge-rows per instruction (uint chunks, 32 lanes/row).
// (r11)  mlp "1 barrier/tile" pipeline held p2[4]+sQ live ACROSS the barrier -> VGPR 96->132,
//        occupancy 10%, 63 us (2x regression). Reverted to r9 mlp: keep nothing live over
//        __syncthreads in multi-wave kernels; registers beat barrier count.

__device__ __forceinline__ float bf2f(unsigned short v) {
  return __uint_as_float(((unsigned int)v) << 16);
}
__device__ __forceinline__ unsigned short f2bf(float f) {
  unsigned int u = __float_as_uint(f);
  return (unsigned short)((u + 0x7fffu + ((u >> 16) & 1u)) >> 16);  // RNE
}

// ---- F1: per-(block, coarse-bucket) histogram of dst ----
__global__ __launch_bounds__(256) void part_hist_kernel(const int* __restrict__ dst,
                                                        int* __restrict__ cnt) {
  __shared__ int h[NBKT];
  const int t = threadIdx.x;
  for (int k = t; k < NBKT; k += 256) h[k] = 0;
  __syncthreads();
  const int base = blockIdx.x * E_PER_BLK;
  for (int i = t; i < E_PER_BLK; i += 256) atomicAdd(&h[dst[base + i] >> 8], 1);
  __syncthreads();
  for (int k = t; k < NBKT; k += 256) cnt[k * F_BLOCKS + blockIdx.x] = h[k];
}

// ---- F2: flat hierarchical exclusive scan over CNT_N entries ----
__global__ __launch_bounds__(256) void scan1g_kernel(const int* __restrict__ in,
                                                     int* __restrict__ ex,
                                                     int* __restrict__ bsum, int n) {
  __shared__ int s[256];
  const int t = threadIdx.x;
  const int i = blockIdx.x * 256 + t;
  int v = (i < n) ? in[i] : 0;
  s[t] = v;
  __syncthreads();
#pragma unroll
  for (int ofs = 1; ofs < 256; ofs <<= 1) {
    int u = (t >= ofs) ? s[t - ofs] : 0;
    __syncthreads();
    s[t] += u;
    __syncthreads();
  }
  if (i < n) ex[i] = s[t] - v;
  if (t == 255) bsum[blockIdx.x] = s[255];
}

__global__ __launch_bounds__(256) void scan2g_kernel(const int* __restrict__ bsum,
                                                     int* __restrict__ bpref, int nb) {
  __shared__ int s[256];
  const int t = threadIdx.x;
  int v = (t < nb) ? bsum[t] : 0;
  s[t] = v;
  __syncthreads();
#pragma unroll
  for (int ofs = 1; ofs < 256; ofs <<= 1) {
    int u = (t >= ofs) ? s[t - ofs] : 0;
    __syncthreads();
    s[t] += u;
    __syncthreads();
  }
  if (t < nb) bpref[t] = s[t] - v;
}

__global__ __launch_bounds__(256) void scan3g_kernel(int* __restrict__ ex,
                                                     const int* __restrict__ bpref, int n) {
  const int i = blockIdx.x * 256 + threadIdx.x;
  if (i < n) ex[i] += bpref[blockIdx.x];
}

// ---- F3: partition edges into coarse-bucket order (LDS cursors) ----
__global__ __launch_bounds__(256) void part_scatter_kernel(const int* __restrict__ src,
                                                           const int* __restrict__ dst,
                                                           const int* __restrict__ cex,
                                                           int* __restrict__ psrc,
                                                           int* __restrict__ pdst) {
  __shared__ int cur[NBKT];
  const int t = threadIdx.x;
  for (int k = t; k < NBKT; k += 256) cur[k] = cex[k * F_BLOCKS + blockIdx.x];
  __syncthreads();
  const int base = blockIdx.x * E_PER_BLK;
  for (int i = t; i < E_PER_BLK; i += 256) {
    int d = dst[base + i], s = src[base + i];
    int p = atomicAdd(&cur[d >> 8], 1);
    pdst[p] = d;
    psrc[p] = s;
  }
}

// ---- F4: per-bucket local counting sort -> csr + off ----
__global__ __launch_bounds__(256) void bucket_sort_kernel(const int* __restrict__ psrc,
                                                          const int* __restrict__ pdst,
                                                          const int* __restrict__ cex,
                                                          int* __restrict__ csr,
                                                          int* __restrict__ off) {
  const int k = blockIdx.x;
  const int t = threadIdx.x;
  const int b0 = cex[k * F_BLOCKS];
  const int b1 = (k == NBKT - 1) ? N_EDGES : cex[(k + 1) * F_BLOCKS];
  __shared__ int cnt[256];
  __shared__ int s[256];
  __shared__ int cur[256];
  cnt[t] = 0;
  __syncthreads();
  for (int i = b0 + t; i < b1; i += 256) atomicAdd(&cnt[pdst[i] & 255], 1);
  __syncthreads();
  int v = cnt[t];
  s[t] = v;
  __syncthreads();
#pragma unroll
  for (int ofs = 1; ofs < 256; ofs <<= 1) {
    int u = (t >= ofs) ? s[t - ofs] : 0;
    __syncthreads();
    s[t] += u;
    __syncthreads();
  }
  const int node = (k << 8) + t;
  const int start = b0 + s[t] - v;
  cur[t] = start;
  if (node < N_NODES) off[node] = start;
  if (k == NBKT - 1 && t == 0) off[N_NODES] = N_EDGES;
  __syncthreads();
  for (int i = b0 + t; i < b1; i += 256) {
    int d = pdst[i];
    int p = atomicAdd(&cur[d & 255], 1);
    csr[p] = psrc[i];
  }
}

// ---- proj: h = relu(x @ Wp + bp). Split-K wave pairs, 4-node tiles, bf16 out ----
__global__ __launch_bounds__(256) void proj_kernel(
    const float* __restrict__ x, const float* __restrict__ Wp,
    const float* __restrict__ bp, unsigned short* __restrict__ h) {
  __shared__ __align__(16) float sX[2][2][4][64];     // [pair][khalf][t][k]
  __shared__ __align__(16) float sPart[2][2][4][64];  // [pair][buf][t][j]
  const int wave = threadIdx.x >> 6, lane = threadIdx.x & 63;
  const int pair = wave >> 1, khalf = wave & 1;
  float w[64];
#pragma unroll
  for (int k = 0; k < 64; ++k) w[k] = Wp[(khalf * 64 + k) * HID + lane];  // coalesced
  const float bias = bp[lane];
  const int pv = blockIdx.x * 2 + pair;
  const int np = gridDim.x * 2;
  const int iters = (NTILES - blockIdx.x * 2 + np - 1) / np;  // block-uniform
  for (int it = 0; it < iters; ++it) {
    const int tile = pv + it * np;
    const bool act = (tile < NTILES);
    const int n0 = tile * 4;
    const int buf = it & 1;
    if (act) {
#pragma unroll
      for (int t = 0; t < 4; ++t)
        sX[pair][khalf][t][lane] = x[(n0 + t) * IN_DIM + khalf * 64 + lane];
    }
    float p[4];
#pragma unroll
    for (int t = 0; t < 4; ++t) {
      float a0 = khalf ? 0.f : bias, a1 = 0.f, a2 = 0.f, a3 = 0.f;
#pragma unroll
      for (int k = 0; k < 64; k += 4) {
        float4 v = *(const float4*)&sX[pair][khalf][t][k];  // same-addr broadcast
        a0 = fmaf(v.x, w[k + 0], a0);
        a1 = fmaf(v.y, w[k + 1], a1);
        a2 = fmaf(v.z, w[k + 2], a2);
        a3 = fmaf(v.w, w[k + 3], a3);
      }
      p[t] = (a0 + a1) + (a2 + a3);
    }
    if (act && khalf) {
#pragma unroll
      for (int t = 0; t < 4; ++t) sPart[pair][buf][t][lane] = p[t];
    }
    __syncthreads();
    if (act && !khalf) {
#pragma unroll
      for (int t = 0; t < 4; ++t)
        h[(n0 + t) * HID + lane] = f2bf(fmaxf(p[t] + sPart[pair][buf][t][lane], 0.0f));
    }
  }
}

// ------- gather: agg[n] = h[n] + sum h[csr[e]] ; 2 edge-rows per load (uint chunks) -------
__global__ __launch_bounds__(256) void gather_kernel(
    const unsigned short* __restrict__ h, const int* __restrict__ off,
    const int* __restrict__ csr, unsigned short* __restrict__ agg) {
  const unsigned int* __restrict__ h2 = (const unsigned int*)h;
  unsigned int* __restrict__ agg2 = (unsigned int*)agg;
  const int lane = threadIdx.x & 63;
  const int half = lane >> 5;   // which edge of a pair
  const int c = lane & 31;      // uint chunk (2 bf16)
  const int wv = (blockIdx.x * 256 + threadIdx.x) >> 6;
  const int nw = (gridDim.x * 256) >> 6;
  for (int n = wv; n < N_NODES; n += nw) {
    const int o0 = off[n], o1 = off[n + 1];
    float ax0 = 0.f, ay0 = 0.f, ax1 = 0.f, ay1 = 0.f;
    float ax2 = 0.f, ay2 = 0.f, ax3 = 0.f, ay3 = 0.f;
    float ax4 = 0.f, ay4 = 0.f, ax5 = 0.f, ay5 = 0.f;
    float ax6 = 0.f, ay6 = 0.f, ax7 = 0.f, ay7 = 0.f;
    if (half == 0) {  // self (eps = 0), counted once
      unsigned int u = h2[n * 32 + c];
      ax0 = bf2f((unsigned short)(u & 0xffff));
      ay0 = bf2f((unsigned short)(u >> 16));
    }
    for (int base = o0; base < o1; base += 64) {
      const int cnt = min(64, o1 - base);
      int idxv = (lane < cnt) ? csr[base + lane] : 0;
      int k = 0;
      for (; k + 16 <= cnt; k += 16) {  // 8 load-pairs = 16 edges in flight
        int i0 = __shfl(idxv, k + 0 + half);
        int i1 = __shfl(idxv, k + 2 + half);
        int i2 = __shfl(idxv, k + 4 + half);
        int i3 = __shfl(idxv, k + 6 + half);
        int i4 = __shfl(idxv, k + 8 + half);
        int i5 = __shfl(idxv, k + 10 + half);
        int i6 = __shfl(idxv, k + 12 + half);
        int i7 = __shfl(idxv, k + 14 + half);
        unsigned int u0 = h2[i0 * 32 + c];
        unsigned int u1 = h2[i1 * 32 + c];
        unsigned int u2 = h2[i2 * 32 + c];
        unsigned int u3 = h2[i3 * 32 + c];
        unsigned int u4 = h2[i4 * 32 + c];
        unsigned int u5 = h2[i5 * 32 + c];
        unsigned int u6 = h2[i6 * 32 + c];
        unsigned int u7 = h2[i7 * 32 + c];
        ax0 += bf2f((unsigned short)(u0 & 0xffff)); ay0 += bf2f((unsigned short)(u0 >> 16));
        ax1 += bf2f((unsigned short)(u1 & 0xffff)); ay1 += bf2f((unsigned short)(u1 >> 16));
        ax2 += bf2f((unsigned short)(u2 & 0xffff)); ay2 += bf2f((unsigned short)(u2 >> 16));
        ax3 += bf2f((unsigned short)(u3 & 0xffff)); ay3 += bf2f((unsigned short)(u3 >> 16));
        ax4 += bf2f((unsigned short)(u4 & 0xffff)); ay4 += bf2f((unsigned short)(u4 >> 16));
        ax5 += bf2f((unsigned short)(u5 & 0xffff)); ay5 += bf2f((unsigned short)(u5 >> 16));
        ax6 += bf2f((unsigned short)(u6 & 0xffff)); ay6 += bf2f((unsigned short)(u6 >> 16));
        ax7 += bf2f((unsigned short)(u7 & 0xffff)); ay7 += bf2f((unsigned short)(u7 >> 16));
      }
      for (; k < cnt; k += 2) {  // tail, 2 edges at a time (high half predicated)
        int ke = k + half;
        int ie = __shfl(idxv, (ke < cnt) ? ke : k);
        unsigned int u = h2[ie * 32 + c];
        if (ke < cnt) {
          ax0 += bf2f((unsigned short)(u & 0xffff));
          ay0 += bf2f((unsigned short)(u >> 16));
        }
      }
    }
    float sx = ((ax0 + ax1) + (ax2 + ax3)) + ((ax4 + ax5) + (ax6 + ax7));
    float sy = ((ay0 + ay1) + (ay2 + ay3)) + ((ay4 + ay5) + (ay6 + ay7));
    sx += __shfl_xor(sx, 32);
    sy += __shfl_xor(sy, 32);
    if (half == 0)
      agg2[n * 32 + c] = (unsigned int)f2bf(sx) | ((unsigned int)f2bf(sy) << 16);
  }
}

// ---- mlp: out = relu(relu(in@W1+b1)@W2+b2). Split-K pairs, 4-node tiles, bf16 (r9 exact) ----
__global__ __launch_bounds__(256) void mlp_kernel(
    const unsigned short* __restrict__ agg, const float* __restrict__ W1,
    const float* __restrict__ b1, const float* __restrict__ W2,
    const float* __restrict__ b2, unsigned short* __restrict__ out) {
  __shared__ __align__(16) float sIn[2][2][4][32];       // [pair][khalf][t][k]
  __shared__ __align__(16) float sP[2][2][2][4][64];     // [pair][khalf][buf][t][j]
  __shared__ __align__(16) float sQ[2][2][4][64];        // [pair][buf][t][j]
  const int wave = threadIdx.x >> 6, lane = threadIdx.x & 63;
  const int pair = wave >> 1, khalf = wave & 1;
  float w1[32], w2[32];
#pragma unroll
  for (int k = 0; k < 32; ++k) w1[k] = W1[(khalf * 32 + k) * HID + lane];
#pragma unroll
  for (int k = 0; k < 32; ++k) w2[k] = W2[(khalf * 32 + k) * HID + lane];
  const float bias1 = b1[lane], bias2 = b2[lane];
  const int pv = blockIdx.x * 2 + pair;
  const int np = gridDim.x * 2;
  const int iters = (NTILES - blockIdx.x * 2 + np - 1) / np;  // block-uniform
  for (int it = 0; it < iters; ++it) {
    const int tile = pv + it * np;
    const bool act = (tile < NTILES);
    const int n0 = tile * 4;
    const int buf = it & 1;
    if (act) {
#pragma unroll
      for (int t = 0; t < 4; ++t)
        sIn[pair][khalf][t][lane & 31] =
            bf2f(agg[(n0 + t) * HID + khalf * 32 + (lane & 31)]);
    }
    float p1[4];
#pragma unroll
    for (int t = 0; t < 4; ++t) {
      float a0 = khalf ? 0.f : bias1, a1 = 0.f, a2 = 0.f, a3 = 0.f;
#pragma unroll
      for (int k = 0; k < 32; k += 4) {
        float4 v = *(const float4*)&sIn[pair][khalf][t][k];
        a0 = fmaf(v.x, w1[k + 0], a0);
        a1 = fmaf(v.y, w1[k + 1], a1);
        a2 = fmaf(v.z, w1[k + 2], a2);
        a3 = fmaf(v.w, w1[k + 3], a3);
      }
      p1[t] = (a0 + a1) + (a2 + a3);
    }
    if (act) {
#pragma unroll
      for (int t = 0; t < 4; ++t) sP[pair][khalf][buf][t][lane] = p1[t];
    }
    __syncthreads();
    float p2[4];
#pragma unroll
    for (int t = 0; t < 4; ++t) {
      float a0 = khalf ? 0.f : bias2, a1 = 0.f, a2 = 0.f, a3 = 0.f;
#pragma unroll
      for (int k = 0; k < 32; k += 4) {
        float4 pa = *(const float4*)&sP[pair][0][buf][t][khalf * 32 + k];
        float4 pb = *(const float4*)&sP[pair][1][buf][t][khalf * 32 + k];
        a0 = fmaf(fmaxf(pa.x + pb.x, 0.0f), w2[k + 0], a0);
        a1 = fmaf(fmaxf(pa.y + pb.y, 0.0f), w2[k + 1], a1);
        a2 = fmaf(fmaxf(pa.z + pb.z, 0.0f), w2[k + 2], a2);
        a3 = fmaf(fmaxf(pa.w + pb.w, 0.0f), w2[k + 3], a3);
      }
      p2[t] = (a0 + a1) + (a2 + a3);
    }
    if (act && khalf) {
#pragma unroll
      for (int t = 0; t < 4; ++t) sQ[pair][buf][t][lane] = p2[t];
    }
    __syncthreads();
    if (act && !khalf) {
#pragma unroll
      for (int t = 0; t < 4; ++t)
        out[(n0 + t) * HID + lane] = f2bf(fmaxf(p2[t] + sQ[pair][buf][t][lane], 0.0f));
    }
  }
}

// ------- pool: batch sorted -> one block per graph, binary-search range -------
__global__ __launch_bounds__(256) void pool_kernel(const unsigned short* __restrict__ h,
                                                   const int* __restrict__ batch,
                                                   float* __restrict__ out) {
  const int g = blockIdx.x;
  int lo = 0, hi = N_NODES;
  while (lo < hi) {
    int mid = (lo + hi) >> 1;
    if (batch[mid] < g) lo = mid + 1; else hi = mid;
  }
  const int s = lo;
  hi = N_NODES;
  while (lo < hi) {
    int mid = (lo + hi) >> 1;
    if (batch[mid] < g + 1) lo = mid + 1; else hi = mid;
  }
  const int e = lo;
  const int wave = threadIdx.x >> 6, lane = threadIdx.x & 63;
  float a0 = 0.f, a1 = 0.f, a2 = 0.f, a3 = 0.f;
  int n = s + wave;
  for (; n + 12 < e; n += 16) {
    a0 += bf2f(h[n * HID + lane]);
    a1 += bf2f(h[(n + 4) * HID + lane]);
    a2 += bf2f(h[(n + 8) * HID + lane]);
    a3 += bf2f(h[(n + 12) * HID + lane]);
  }
  for (; n < e; n += 4) a0 += bf2f(h[n * HID + lane]);
  __shared__ float red[4][HID];
  red[wave][lane] = ((a0 + a1) + (a2 + a3));
  __syncthreads();
  if (wave == 0) {
    float v = red[0][lane] + red[1][lane] + red[2][lane] + red[3][lane];
    float cnt = (float)(e - s);
    out[g * HID + lane] = v / fmaxf(cnt, 1.0f);
  }
}

extern "C" void kernel_launch(void* const* d_in, const int* in_sizes, int n_in,
                              void* d_out, int out_size, void* d_ws, size_t ws_size,
                              hipStream_t stream) {
  const float* x    = (const float*)d_in[0];
  const int*   edge = (const int*)d_in[1];
  const int*   batch= (const int*)d_in[2];
  const float* Wp   = (const float*)d_in[3];
  const float* bp   = (const float*)d_in[4];
  const float* W1_0 = (const float*)d_in[5];
  const float* b1_0 = (const float*)d_in[6];
  const float* W2_0 = (const float*)d_in[7];
  const float* b2_0 = (const float*)d_in[8];
  const float* W1_1 = (const float*)d_in[9];
  const float* b1_1 = (const float*)d_in[10];
  const float* W2_1 = (const float*)d_in[11];
  const float* b2_1 = (const float*)d_in[12];
  const int* src = edge;
  const int* dst = edge + N_EDGES;
  float* out = (float*)d_out;

  const size_t NB = (size_t)N_NODES * HID;
  unsigned short* hA = (unsigned short*)d_ws;  // NB bf16
  unsigned short* hB = hA + NB;                // NB bf16
  int* off     = (int*)(hB + NB);   // N_NODES+1
  int* cnt     = off + N_NODES + 1; // CNT_N
  int* cex     = cnt + CNT_N;       // CNT_N
  int* sbsum   = cex + CNT_N;       // SCB
  int* sbpref  = sbsum + SCB;       // SCB
  int* pdst    = sbpref + SCB;      // N_EDGES
  int* psrc    = pdst + N_EDGES;    // N_EDGES
  int* csr     = psrc + N_EDGES;    // N_EDGES

  dim3 b256(256);

  // CSR build: counting sort, zero global atomics
  part_hist_kernel<<<F_BLOCKS, b256, 0, stream>>>(dst, cnt);
  scan1g_kernel<<<SCB, b256, 0, stream>>>(cnt, cex, sbsum, CNT_N);
  scan2g_kernel<<<1, b256, 0, stream>>>(sbsum, sbpref, SCB);
  scan3g_kernel<<<SCB, b256, 0, stream>>>(cex, sbpref, CNT_N);
  part_scatter_kernel<<<F_BLOCKS, b256, 0, stream>>>(src, dst, cex, psrc, pdst);
  bucket_sort_kernel<<<NBKT, b256, 0, stream>>>(psrc, pdst, cex, csr, off);

  // h0 -> hA
  proj_kernel<<<2048, b256, 0, stream>>>(x, Wp, bp, hA);

  // layer 0: gather A->B, mlp B->B (in-place)
  gather_kernel<<<12500, b256, 0, stream>>>(hA, off, csr, hB);
  mlp_kernel<<<2048, b256, 0, stream>>>(hB, W1_0, b1_0, W2_0, b2_0, hB);

  // layer 1: gather B->A, mlp A->A (in-place)
  gather_kernel<<<12500, b256, 0, stream>>>(hB, off, csr, hA);
  mlp_kernel<<<2048, b256, 0, stream>>>(hA, W1_1, b1_1, W2_1, b2_1, hA);

  // pool
  pool_kernel<<<N_GRAPHS, b256, 0, stream>>>(hA, batch, out);
}

// Round 13
// 140.821 us; speedup vs baseline: 1.7097x; 1.2417x over previous
//
#include <hip/hip_runtime.h>

#define N_NODES 50000
#define N_EDGES 800000
#define IN_DIM 128
#define HID 64
#define N_GRAPHS 256

#define E_PER_BLK 4000
#define F_BLOCKS (N_EDGES / E_PER_BLK)      // 200
#define NBKT ((N_NODES + 255) / 256)        // 196 coarse buckets of 256 nodes
#define CNT_N (NBKT * F_BLOCKS)             // 39200
#define SCB ((CNT_N + 255) / 256)           // 154
#define NTILES (N_NODES / 4)                // 12500 (exact)
#define MTILES (N_NODES / 16)               // 3125 mfma node-tiles (exact)

// NOTES:
// (r3-4) __launch_bounds__ min-waves arg => VGPR cap halved, ~1.1 GB scratch spill. Plain (256).
// (r5)   single-block scan = 125 us one-CU latency; hierarchical scans only.
// (r6)   GEMV with LDS-resident W was LDS-pipe-bound (256 DS ops/node).
// (r7)   atomic-cursor CSR fill (800K device atomics) -> LDS counting sort.
// (r8)   big per-lane W arrays -> compiler caps ~85 VGPR and REMATERIALIZES weight loads.
// (r9)   per-node barriers ate the gain -> 4-node tiles + bf16 node buffers.
// (r10)  gather loads 2 edge-rows per instruction (uint chunks, 32 lanes/row).
// (r11)  values live ACROSS __syncthreads -> VGPR 132, occupancy 10%, 2x regression. Reverted.
// (r12)  mlp -> MFMA (16x16x32 bf16): weights in LDS in fragment order (1 ds_read_b128/frag),
//        L1->L2 transpose via padded per-wave LDS tile, coalesced uint4 store via LDS.

__device__ __forceinline__ float bf2f(unsigned short v) {
  return __uint_as_float(((unsigned int)v) << 16);
}
__device__ __forceinline__ unsigned short f2bf(float f) {
  unsigned int u = __float_as_uint(f);
  return (unsigned short)((u + 0x7fffu + ((u >> 16) & 1u)) >> 16);  // RNE
}

typedef __attribute__((ext_vector_type(8))) short bf16x8;
typedef __attribute__((ext_vector_type(4))) float f32x4;

// ---- F1: per-(block, coarse-bucket) histogram of dst ----
__global__ __launch_bounds__(256) void part_hist_kernel(const int* __restrict__ dst,
                                                        int* __restrict__ cnt) {
  __shared__ int h[NBKT];
  const int t = threadIdx.x;
  for (int k = t; k < NBKT; k += 256) h[k] = 0;
  __syncthreads();
  const int base = blockIdx.x * E_PER_BLK;
  for (int i = t; i < E_PER_BLK; i += 256) atomicAdd(&h[dst[base + i] >> 8], 1);
  __syncthreads();
  for (int k = t; k < NBKT; k += 256) cnt[k * F_BLOCKS + blockIdx.x] = h[k];
}

// ---- F2: flat hierarchical exclusive scan over CNT_N entries ----
__global__ __launch_bounds__(256) void scan1g_kernel(const int* __restrict__ in,
                                                     int* __restrict__ ex,
                                                     int* __restrict__ bsum, int n) {
  __shared__ int s[256];
  const int t = threadIdx.x;
  const int i = blockIdx.x * 256 + t;
  int v = (i < n) ? in[i] : 0;
  s[t] = v;
  __syncthreads();
#pragma unroll
  for (int ofs = 1; ofs < 256; ofs <<= 1) {
    int u = (t >= ofs) ? s[t - ofs] : 0;
    __syncthreads();
    s[t] += u;
    __syncthreads();
  }
  if (i < n) ex[i] = s[t] - v;
  if (t == 255) bsum[blockIdx.x] = s[255];
}

__global__ __launch_bounds__(256) void scan2g_kernel(const int* __restrict__ bsum,
                                                     int* __restrict__ bpref, int nb) {
  __shared__ int s[256];
  const int t = threadIdx.x;
  int v = (t < nb) ? bsum[t] : 0;
  s[t] = v;
  __syncthreads();
#pragma unroll
  for (int ofs = 1; ofs < 256; ofs <<= 1) {
    int u = (t >= ofs) ? s[t - ofs] : 0;
    __syncthreads();
    s[t] += u;
    __syncthreads();
  }
  if (t < nb) bpref[t] = s[t] - v;
}

__global__ __launch_bounds__(256) void scan3g_kernel(int* __restrict__ ex,
                                                     const int* __restrict__ bpref, int n) {
  const int i = blockIdx.x * 256 + threadIdx.x;
  if (i < n) ex[i] += bpref[blockIdx.x];
}

// ---- F3: partition edges into coarse-bucket order (LDS cursors) ----
__global__ __launch_bounds__(256) void part_scatter_kernel(const int* __restrict__ src,
                                                           const int* __restrict__ dst,
                                                           const int* __restrict__ cex,
                                                           int* __restrict__ psrc,
                                                           int* __restrict__ pdst) {
  __shared__ int cur[NBKT];
  const int t = threadIdx.x;
  for (int k = t; k < NBKT; k += 256) cur[k] = cex[k * F_BLOCKS + blockIdx.x];
  __syncthreads();
  const int base = blockIdx.x * E_PER_BLK;
  for (int i = t; i < E_PER_BLK; i += 256) {
    int d = dst[base + i], s = src[base + i];
    int p = atomicAdd(&cur[d >> 8], 1);
    pdst[p] = d;
    psrc[p] = s;
  }
}

// ---- F4: per-bucket local counting sort -> csr + off ----
__global__ __launch_bounds__(256) void bucket_sort_kernel(const int* __restrict__ psrc,
                                                          const int* __restrict__ pdst,
                                                          const int* __restrict__ cex,
                                                          int* __restrict__ csr,
                                                          int* __restrict__ off) {
  const int k = blockIdx.x;
  const int t = threadIdx.x;
  const int b0 = cex[k * F_BLOCKS];
  const int b1 = (k == NBKT - 1) ? N_EDGES : cex[(k + 1) * F_BLOCKS];
  __shared__ int cnt[256];
  __shared__ int s[256];
  __shared__ int cur[256];
  cnt[t] = 0;
  __syncthreads();
  for (int i = b0 + t; i < b1; i += 256) atomicAdd(&cnt[pdst[i] & 255], 1);
  __syncthreads();
  int v = cnt[t];
  s[t] = v;
  __syncthreads();
#pragma unroll
  for (int ofs = 1; ofs < 256; ofs <<= 1) {
    int u = (t >= ofs) ? s[t - ofs] : 0;
    __syncthreads();
    s[t] += u;
    __syncthreads();
  }
  const int node = (k << 8) + t;
  const int start = b0 + s[t] - v;
  cur[t] = start;
  if (node < N_NODES) off[node] = start;
  if (k == NBKT - 1 && t == 0) off[N_NODES] = N_EDGES;
  __syncthreads();
  for (int i = b0 + t; i < b1; i += 256) {
    int d = pdst[i];
    int p = atomicAdd(&cur[d & 255], 1);
    csr[p] = psrc[i];
  }
}

// ---- proj: h = relu(x @ Wp + bp). Split-K wave pairs, 4-node tiles, bf16 out ----
__global__ __launch_bounds__(256) void proj_kernel(
    const float* __restrict__ x, const float* __restrict__ Wp,
    const float* __restrict__ bp, unsigned short* __restrict__ h) {
  __shared__ __align__(16) float sX[2][2][4][64];     // [pair][khalf][t][k]
  __shared__ __align__(16) float sPart[2][2][4][64];  // [pair][buf][t][j]
  const int wave = threadIdx.x >> 6, lane = threadIdx.x & 63;
  const int pair = wave >> 1, khalf = wave & 1;
  float w[64];
#pragma unroll
  for (int k = 0; k < 64; ++k) w[k] = Wp[(khalf * 64 + k) * HID + lane];  // coalesced
  const float bias = bp[lane];
  const int pv = blockIdx.x * 2 + pair;
  const int np = gridDim.x * 2;
  const int iters = (NTILES - blockIdx.x * 2 + np - 1) / np;  // block-uniform
  for (int it = 0; it < iters; ++it) {
    const int tile = pv + it * np;
    const bool act = (tile < NTILES);
    const int n0 = tile * 4;
    const int buf = it & 1;
    if (act) {
#pragma unroll
      for (int t = 0; t < 4; ++t)
        sX[pair][khalf][t][lane] = x[(n0 + t) * IN_DIM + khalf * 64 + lane];
    }
    float p[4];
#pragma unroll
    for (int t = 0; t < 4; ++t) {
      float a0 = khalf ? 0.f : bias, a1 = 0.f, a2 = 0.f, a3 = 0.f;
#pragma unroll
      for (int k = 0; k < 64; k += 4) {
        float4 v = *(const float4*)&sX[pair][khalf][t][k];  // same-addr broadcast
        a0 = fmaf(v.x, w[k + 0], a0);
        a1 = fmaf(v.y, w[k + 1], a1);
        a2 = fmaf(v.z, w[k + 2], a2);
        a3 = fmaf(v.w, w[k + 3], a3);
      }
      p[t] = (a0 + a1) + (a2 + a3);
    }
    if (act && khalf) {
#pragma unroll
      for (int t = 0; t < 4; ++t) sPart[pair][buf][t][lane] = p[t];
    }
    __syncthreads();
    if (act && !khalf) {
#pragma unroll
      for (int t = 0; t < 4; ++t)
        h[(n0 + t) * HID + lane] = f2bf(fmaxf(p[t] + sPart[pair][buf][t][lane], 0.0f));
    }
  }
}

// ------- gather: agg[n] = h[n] + sum h[csr[e]] ; 2 edge-rows per load (uint chunks) -------
__global__ __launch_bounds__(256) void gather_kernel(
    const unsigned short* __restrict__ h, const int* __restrict__ off,
    const int* __restrict__ csr, unsigned short* __restrict__ agg) {
  const unsigned int* __restrict__ h2 = (const unsigned int*)h;
  unsigned int* __restrict__ agg2 = (unsigned int*)agg;
  const int lane = threadIdx.x & 63;
  const int half = lane >> 5;   // which edge of a pair
  const int c = lane & 31;      // uint chunk (2 bf16)
  const int wv = (blockIdx.x * 256 + threadIdx.x) >> 6;
  const int nw = (gridDim.x * 256) >> 6;
  for (int n = wv; n < N_NODES; n += nw) {
    const int o0 = off[n], o1 = off[n + 1];
    float ax0 = 0.f, ay0 = 0.f, ax1 = 0.f, ay1 = 0.f;
    float ax2 = 0.f, ay2 = 0.f, ax3 = 0.f, ay3 = 0.f;
    float ax4 = 0.f, ay4 = 0.f, ax5 = 0.f, ay5 = 0.f;
    float ax6 = 0.f, ay6 = 0.f, ax7 = 0.f, ay7 = 0.f;
    if (half == 0) {  // self (eps = 0), counted once
      unsigned int u = h2[n * 32 + c];
      ax0 = bf2f((unsigned short)(u & 0xffff));
      ay0 = bf2f((unsigned short)(u >> 16));
    }
    for (int base = o0; base < o1; base += 64) {
      const int cnt = min(64, o1 - base);
      int idxv = (lane < cnt) ? csr[base + lane] : 0;
      int k = 0;
      for (; k + 16 <= cnt; k += 16) {  // 8 load-pairs = 16 edges in flight
        int i0 = __shfl(idxv, k + 0 + half);
        int i1 = __shfl(idxv, k + 2 + half);
        int i2 = __shfl(idxv, k + 4 + half);
        int i3 = __shfl(idxv, k + 6 + half);
        int i4 = __shfl(idxv, k + 8 + half);
        int i5 = __shfl(idxv, k + 10 + half);
        int i6 = __shfl(idxv, k + 12 + half);
        int i7 = __shfl(idxv, k + 14 + half);
        unsigned int u0 = h2[i0 * 32 + c];
        unsigned int u1 = h2[i1 * 32 + c];
        unsigned int u2 = h2[i2 * 32 + c];
        unsigned int u3 = h2[i3 * 32 + c];
        unsigned int u4 = h2[i4 * 32 + c];
        unsigned int u5 = h2[i5 * 32 + c];
        unsigned int u6 = h2[i6 * 32 + c];
        unsigned int u7 = h2[i7 * 32 + c];
        ax0 += bf2f((unsigned short)(u0 & 0xffff)); ay0 += bf2f((unsigned short)(u0 >> 16));
        ax1 += bf2f((unsigned short)(u1 & 0xffff)); ay1 += bf2f((unsigned short)(u1 >> 16));
        ax2 += bf2f((unsigned short)(u2 & 0xffff)); ay2 += bf2f((unsigned short)(u2 >> 16));
        ax3 += bf2f((unsigned short)(u3 & 0xffff)); ay3 += bf2f((unsigned short)(u3 >> 16));
        ax4 += bf2f((unsigned short)(u4 & 0xffff)); ay4 += bf2f((unsigned short)(u4 >> 16));
        ax5 += bf2f((unsigned short)(u5 & 0xffff)); ay5 += bf2f((unsigned short)(u5 >> 16));
        ax6 += bf2f((unsigned short)(u6 & 0xffff)); ay6 += bf2f((unsigned short)(u6 >> 16));
        ax7 += bf2f((unsigned short)(u7 & 0xffff)); ay7 += bf2f((unsigned short)(u7 >> 16));
      }
      for (; k < cnt; k += 2) {  // tail, 2 edges at a time (high half predicated)
        int ke = k + half;
        int ie = __shfl(idxv, (ke < cnt) ? ke : k);
        unsigned int u = h2[ie * 32 + c];
        if (ke < cnt) {
          ax0 += bf2f((unsigned short)(u & 0xffff));
          ay0 += bf2f((unsigned short)(u >> 16));
        }
      }
    }
    float sx = ((ax0 + ax1) + (ax2 + ax3)) + ((ax4 + ax5) + (ax6 + ax7));
    float sy = ((ay0 + ay1) + (ay2 + ay3)) + ((ay4 + ay5) + (ay6 + ay7));
    sx += __shfl_xor(sx, 32);
    sy += __shfl_xor(sy, 32);
    if (half == 0)
      agg2[n * 32 + c] = (unsigned int)f2bf(sx) | ((unsigned int)f2bf(sy) << 16);
  }
}

// ---- mlp (MFMA): out = relu(relu(in@W1+b1)@W2+b2), 16-node tiles per wave ----
// Weights staged in LDS in fragment order: frag f=(nc*2+ks), lane l, elem e -> one
// ds_read_b128 per B-fragment. Element W[k][j] lives at lane ((k>>3)&3)*16+(j&15),
// frag (j>>4)*2+(k>>5), elem k&7.  A-frag: row=lane&15, k=(lane>>4)*8+e (contiguous).
// C/D: col=lane&15, row=(lane>>4)*4+reg.
__global__ __launch_bounds__(256) void mlp_mfma_kernel(
    const unsigned short* __restrict__ agg, const float* __restrict__ W1,
    const float* __restrict__ b1, const float* __restrict__ W2,
    const float* __restrict__ b2, unsigned short* __restrict__ out) {
  __shared__ __align__(16) unsigned short sW1[4096];     // 8 KB, fragment-ordered
  __shared__ __align__(16) unsigned short sW2[4096];     // 8 KB
  __shared__ __align__(16) unsigned short sT[4][16][72]; // per-wave transpose, pad->144B rows
  const int t = threadIdx.x;
  for (int i = t; i < 4096; i += 256) {
    const int k = i >> 6, j = i & 63;
    const int pos = (((j >> 4) * 2 + (k >> 5)) * 64 + ((k >> 3) & 3) * 16 + (j & 15)) * 8 + (k & 7);
    sW1[pos] = f2bf(W1[i]);
    sW2[pos] = f2bf(W2[i]);
  }
  __syncthreads();
  const int wave = t >> 6, lane = t & 63;
  const int row = lane & 15;   // A-row / D-col
  const int kgrp = lane >> 4;  // 0..3
  float bias1[4], bias2[4];
#pragma unroll
  for (int nc = 0; nc < 4; ++nc) {
    bias1[nc] = b1[nc * 16 + row];
    bias2[nc] = b2[nc * 16 + row];
  }
  const int wtile = blockIdx.x * 4 + wave;
  const int ntile = gridDim.x * 4;
  for (int tile = wtile; tile < MTILES; tile += ntile) {
    const int n0 = tile * 16;
    bf16x8 a1[2];
    a1[0] = *(const bf16x8*)&agg[(n0 + row) * HID + kgrp * 8];
    a1[1] = *(const bf16x8*)&agg[(n0 + row) * HID + 32 + kgrp * 8];
    f32x4 acc;
#pragma unroll
    for (int nc = 0; nc < 4; ++nc) {
      acc = (f32x4){bias1[nc], bias1[nc], bias1[nc], bias1[nc]};
#pragma unroll
      for (int ks = 0; ks < 2; ++ks) {
        bf16x8 bf = *(const bf16x8*)&sW1[((nc * 2 + ks) * 64 + lane) * 8];
        acc = __builtin_amdgcn_mfma_f32_16x16x32_bf16(a1[ks], bf, acc, 0, 0, 0);
      }
#pragma unroll
      for (int r = 0; r < 4; ++r)
        sT[wave][kgrp * 4 + r][nc * 16 + row] = f2bf(fmaxf(acc[r], 0.0f));
    }
    bf16x8 a2[2];
    a2[0] = *(const bf16x8*)&sT[wave][row][kgrp * 8];
    a2[1] = *(const bf16x8*)&sT[wave][row][32 + kgrp * 8];
#pragma unroll
    for (int nc = 0; nc < 4; ++nc) {
      acc = (f32x4){bias2[nc], bias2[nc], bias2[nc], bias2[nc]};
#pragma unroll
      for (int ks = 0; ks < 2; ++ks) {
        bf16x8 bf = *(const bf16x8*)&sW2[((nc * 2 + ks) * 64 + lane) * 8];
        acc = __builtin_amdgcn_mfma_f32_16x16x32_bf16(a2[ks], bf, acc, 0, 0, 0);
      }
#pragma unroll
      for (int r = 0; r < 4; ++r)
        sT[wave][kgrp * 4 + r][nc * 16 + row] = f2bf(fmaxf(acc[r], 0.0f));
    }
    // coalesced store: 16 rows x 64 bf16 via uint4 (2 passes of 64 lanes)
#pragma unroll
    for (int p = 0; p < 2; ++p) {
      const int idx = p * 64 + lane;
      const int ri = idx >> 3, ch = idx & 7;
      uint4 v = *(const uint4*)&sT[wave][ri][ch * 8];
      *(uint4*)&out[(n0 + ri) * HID + ch * 8] = v;
    }
  }
}

// ------- pool: batch sorted -> one block per graph, binary-search range -------
__global__ __launch_bounds__(256) void pool_kernel(const unsigned short* __restrict__ h,
                                                   const int* __restrict__ batch,
                                                   float* __restrict__ out) {
  const int g = blockIdx.x;
  int lo = 0, hi = N_NODES;
  while (lo < hi) {
    int mid = (lo + hi) >> 1;
    if (batch[mid] < g) lo = mid + 1; else hi = mid;
  }
  const int s = lo;
  hi = N_NODES;
  while (lo < hi) {
    int mid = (lo + hi) >> 1;
    if (batch[mid] < g + 1) lo = mid + 1; else hi = mid;
  }
  const int e = lo;
  const int wave = threadIdx.x >> 6, lane = threadIdx.x & 63;
  float a0 = 0.f, a1 = 0.f, a2 = 0.f, a3 = 0.f;
  int n = s + wave;
  for (; n + 12 < e; n += 16) {
    a0 += bf2f(h[n * HID + lane]);
    a1 += bf2f(h[(n + 4) * HID + lane]);
    a2 += bf2f(h[(n + 8) * HID + lane]);
    a3 += bf2f(h[(n + 12) * HID + lane]);
  }
  for (; n < e; n += 4) a0 += bf2f(h[n * HID + lane]);
  __shared__ float red[4][HID];
  red[wave][lane] = ((a0 + a1) + (a2 + a3));
  __syncthreads();
  if (wave == 0) {
    float v = red[0][lane] + red[1][lane] + red[2][lane] + red[3][lane];
    float cnt = (float)(e - s);
    out[g * HID + lane] = v / fmaxf(cnt, 1.0f);
  }
}

extern "C" void kernel_launch(void* const* d_in, const int* in_sizes, int n_in,
                              void* d_out, int out_size, void* d_ws, size_t ws_size,
                              hipStream_t stream) {
  const float* x    = (const float*)d_in[0];
  const int*   edge = (const int*)d_in[1];
  const int*   batch= (const int*)d_in[2];
  const float* Wp   = (const float*)d_in[3];
  const float* bp   = (const float*)d_in[4];
  const float* W1_0 = (const float*)d_in[5];
  const float* b1_0 = (const float*)d_in[6];
  const float* W2_0 = (const float*)d_in[7];
  const float* b2_0 = (const float*)d_in[8];
  const float* W1_1 = (const float*)d_in[9];
  const float* b1_1 = (const float*)d_in[10];
  const float* W2_1 = (const float*)d_in[11];
  const float* b2_1 = (const float*)d_in[12];
  const int* src = edge;
  const int* dst = edge + N_EDGES;
  float* out = (float*)d_out;

  const size_t NB = (size_t)N_NODES * HID;
  unsigned short* hA = (unsigned short*)d_ws;  // NB bf16
  unsigned short* hB = hA + NB;                // NB bf16
  int* off     = (int*)(hB + NB);   // N_NODES+1
  int* cnt     = off + N_NODES + 1; // CNT_N
  int* cex     = cnt + CNT_N;       // CNT_N
  int* sbsum   = cex + CNT_N;       // SCB
  int* sbpref  = sbsum + SCB;       // SCB
  int* pdst    = sbpref + SCB;      // N_EDGES
  int* psrc    = pdst + N_EDGES;    // N_EDGES
  int* csr     = psrc + N_EDGES;    // N_EDGES

  dim3 b256(256);

  // CSR build: counting sort, zero global atomics
  part_hist_kernel<<<F_BLOCKS, b256, 0, stream>>>(dst, cnt);
  scan1g_kernel<<<SCB, b256, 0, stream>>>(cnt, cex, sbsum, CNT_N);
  scan2g_kernel<<<1, b256, 0, stream>>>(sbsum, sbpref, SCB);
  scan3g_kernel<<<SCB, b256, 0, stream>>>(cex, sbpref, CNT_N);
  part_scatter_kernel<<<F_BLOCKS, b256, 0, stream>>>(src, dst, cex, psrc, pdst);
  bucket_sort_kernel<<<NBKT, b256, 0, stream>>>(psrc, pdst, cex, csr, off);

  // h0 -> hA
  proj_kernel<<<2048, b256, 0, stream>>>(x, Wp, bp, hA);

  // layer 0: gather A->B, mlp B->B (in-place per-tile: reads before writes)
  gather_kernel<<<12500, b256, 0, stream>>>(hA, off, csr, hB);
  mlp_mfma_kernel<<<256, b256, 0, stream>>>(hB, W1_0, b1_0, W2_0, b2_0, hB);

  // layer 1: gather B->A, mlp A->A
  gather_kernel<<<12500, b256, 0, stream>>>(hB, off, csr, hA);
  mlp_mfma_kernel<<<256, b256, 0, stream>>>(hA, W1_1, b1_1, W2_1, b2_1, hA);

  // pool
  pool_kernel<<<N_GRAPHS, b256, 0, stream>>>(hA, batch, out);
}